// Round 2
// baseline (234.506 us; speedup 1.0000x reference)
//
#include <hip/hip_runtime.h>

typedef float    f32x4 __attribute__((ext_vector_type(4)));
typedef _Float16 f16x2 __attribute__((ext_vector_type(2)));
typedef _Float16 f16x4 __attribute__((ext_vector_type(4)));
typedef _Float16 f16x8 __attribute__((ext_vector_type(8)));
typedef int      i32x4 __attribute__((ext_vector_type(4)));

namespace {
constexpr int B_ = 2, L_ = 2048, S_ = 2048, H_ = 16, E_ = 64;
constexpr int MBLK = 128;        // q rows per block (4 q-subblocks x 32)
constexpr int NT = 64;           // s-tile width
constexpr int NTILES_G = 16;     // s-tiles per group (32 total / 2 groups)

#define SCALE2f 0.1803368801111204f /* 0.125 * log2(e) */
#define MBIAS2f -1.8033688e8f       /* -1e9 * 0.125 * log2(e): exp2 -> exactly 0 */

// ws layout: [0,1MiB) mask bits | Kh f16 [b,h,s,e] 8.39MB | Vh f16 [b,h,e,s] 8.39MB
constexpr size_t KHOFF = (size_t)1 << 20;
constexpr size_t VHOFF = KHOFF + (size_t)B_ * H_ * S_ * E_ * 2;

__device__ __forceinline__ f16x2 cvt2(float a, float b) {
  return __builtin_bit_cast(f16x2, __builtin_amdgcn_cvt_pkrtz(a, b));
}
__device__ __forceinline__ int pkh(float a, float b) {
  return __builtin_bit_cast(int, __builtin_amdgcn_cvt_pkrtz(a, b));
}
union H8 { f16x8 v; i32x4 i; };
union H4 { f16x4 v; f16x2 h[2]; };

#define GLOAD_LDS16(g, l)                                              \
  __builtin_amdgcn_global_load_lds(                                    \
      (const __attribute__((address_space(1))) void*)(g),              \
      (__attribute__((address_space(3))) void*)(l), 16, 0, 0)
}  // namespace

// ---- fused pre-pass: kcvt [0,2048) | maskpack [2048,4096) | vcvt [4096,5120)
// one launch instead of three: removes 2 inter-kernel gaps, overlaps the
// pure-BW mask stream with the gather-heavy K/V conversion streams.
extern "C" __global__ __launch_bounds__(256)
void prep_kernel(const float* __restrict__ Kg, const float* __restrict__ Vg,
                 const float* __restrict__ Mg, _Float16* __restrict__ Kh,
                 _Float16* __restrict__ Vh, unsigned long long* __restrict__ Wb) {
  __shared__ _Float16 T[64][72];
  const int bid = blockIdx.x;
  const int t   = threadIdx.x;

  if (bid < 2048) {
    // K [b,s,h,e] f32 -> Kh [b,h,s,e] f16 (h-gather)
    const int idx = bid * 256 + t;  // 8-e chunk id
    const int j = idx & 7;
    const int h = (idx >> 3) & (H_ - 1);
    const int s = (idx >> 7) & (S_ - 1);
    const int b = idx >> 18;
    const float* src = Kg + ((((size_t)b * S_ + s) * H_ + h) << 6) + j * 8;
    f32x4 x = *(const f32x4*)src, y = *(const f32x4*)(src + 4);
    i32x4 w = {pkh(x[0], x[1]), pkh(x[2], x[3]), pkh(y[0], y[1]), pkh(y[2], y[3])};
    *(i32x4*)(Kh + ((((size_t)b * H_ + h) * S_ + s) << 6) + j * 8) = w;
  } else if (bid < 4096) {
    // mask fp32 -> 1 bit/element; thread: 16 floats (64B coalesced) -> one u16
    const int u = (bid - 2048) * 256 + t;
    const float* src = Mg + (size_t)u * 16;
    unsigned m = 0;
#pragma unroll
    for (int i = 0; i < 4; ++i) {
      f32x4 x = *(const f32x4*)(src + i * 4);
#pragma unroll
      for (int c = 0; c < 4; ++c) m |= (x[c] > 0.5f ? 1u : 0u) << (i * 4 + c);
    }
    ((unsigned short*)Wb)[u] = (unsigned short)m;
  } else {
    // V [b,s,h,e] f32 -> Vh [b,h,e,s] f16 (transpose via LDS)
    const int vb = bid - 4096;  // (b,h,st)
    const int st = vb & 31;
    const int h  = (vb >> 5) & (H_ - 1);
    const int b  = vb >> 9;
    const int sl = t >> 2;
    const int e0 = (t & 3) << 4;
    const float* src = Vg + ((((size_t)b * S_ + st * 64 + sl) * H_ + h) << 6) + e0;
#pragma unroll
    for (int i = 0; i < 4; ++i) {
      f32x4 x = *(const f32x4*)(src + i * 4);
#pragma unroll
      for (int c = 0; c < 4; ++c) T[e0 + i * 4 + c][sl] = (_Float16)x[c];
    }
    __syncthreads();
    const int er = t >> 2;
    const int s0 = (t & 3) << 4;
    _Float16* dst = Vh + (((((size_t)b * H_ + h) << 6) + er) * S_) + st * 64 + s0;
    *(i32x4*)dst       = *(const i32x4*)&T[er][s0];
    *(i32x4*)(dst + 8) = *(const i32x4*)&T[er][s0 + 8];
  }
}

// 8 waves = 2 s-groups x 4 q-subblocks. Each group owns half the s-tiles with
// its own K/V double-buffer -> per-wave LDS reads stay at the 32-row rate
// (round-0 traffic) while occupancy is 16 waves/CU (round-1 level).
extern "C" __global__ __launch_bounds__(512, 4)
void fattn_kernel(const float* __restrict__ Qg, const _Float16* __restrict__ Kh,
                  const _Float16* __restrict__ Vh, const unsigned long long* __restrict__ Wb,
                  float* __restrict__ Og) {
  // [group][K=0/V=1][buf][row][64], 64 KB; DMA dest lane-contiguous (no pad),
  // bank safety via XOR-granule swizzle
  __shared__ __align__(16) _Float16 smem[2][2][2][64][64];

  const int tid  = threadIdx.x;
  const int wv   = tid >> 6;   // 0..7
  const int lane = tid & 63;
  const int g    = wv >> 2;    // s-range group: tiles [g*16, g*16+16)
  const int wq   = wv & 3;     // q sub-block (32 rows)
  const int qd   = lane >> 4;
  const int cl   = lane & 15;
  const int sw   = cl & 7;     // reader swizzle key (row & 7)

  // XCD-locality: bid%8 == bh%8 -> all 16 q-blocks of one (b,h) on one XCD
  const int bid = blockIdx.x;
  const int qb  = bid >> 5;
  const int bh  = bid & 31;
  const int h   = bh & (H_ - 1);
  const int b   = bh >> 4;

  const int l0 = qb * MBLK + wq * 32;  // 32 q rows per wave (2 m-tiles)

  // ---- Q fragments (B-operand of S^T = K Q^T), f16, from f32 global
  f16x8 qf[2][2];
#pragma unroll
  for (int mt = 0; mt < 2; ++mt) {
    const float* qp = Qg + ((((size_t)b * L_ + (l0 + mt * 16 + cl)) * H_ + h) << 6);
#pragma unroll
    for (int kb = 0; kb < 2; ++kb) {
      const int e0 = qd * 8 + kb * 32;
      f32x4 x = *(const f32x4*)(qp + e0);
      f32x4 y = *(const f32x4*)(qp + e0 + 4);
      H8 u;
      u.i = (i32x4){pkh(x[0], x[1]), pkh(x[2], x[3]), pkh(y[0], y[1]), pkh(y[2], y[3])};
      qf[mt][kb] = u.v;
    }
  }

  // ---- DMA lane constants: lane = 8*row_local + granule_slot
  const int rl  = lane >> 3;       // row within 8-row slab (0..7)
  const int gsl = lane & 7;        // granule slot in LDS row
  const int gsw = gsl ^ rl;        // swizzled source granule (row&7 == rl)
  const _Float16* khb = Kh + ((((size_t)b * H_ + h) * S_) << 6);          // [s][e]
  const _Float16* vhb = Vh + ((((size_t)b * H_ + h) << 6) * (size_t)S_);  // [e][s]

  const unsigned long long* wbp = Wb + (((size_t)b * L_ + (l0 + cl)) << 5) + g * NTILES_G;

  // stage one tile of this group's K+V via global_load_lds (16 B/lane)
  auto dma = [&](int buf, int t) {
    const int ts = g * NTILES_G + t;
#pragma unroll
    for (int p = 0; p < 2; ++p) {
      const int r0 = p * 32 + wq * 8;
      const _Float16* ksrc = khb + (((size_t)(ts * 64 + r0 + rl)) << 6) + gsw * 8;
      GLOAD_LDS16(ksrc, &smem[g][0][buf][r0][0]);
      const _Float16* vsrc = vhb + (size_t)(r0 + rl) * S_ + ts * 64 + gsw * 8;
      GLOAD_LDS16(vsrc, &smem[g][1][buf][r0][0]);
    }
  };

  const f32x4 zero4 = {0.f, 0.f, 0.f, 0.f};
  f32x4 acc[2][4];
#pragma unroll
  for (int mt = 0; mt < 2; ++mt)
#pragma unroll
    for (int et = 0; et < 4; ++et) acc[mt][et] = zero4;
  f32x4 rs4[2] = {zero4, zero4};

  dma(0, 0);
  unsigned long long mwcur = wbp[0];

  for (int t = 0; t < NTILES_G; ++t) {
    const int cb = t & 1;
    __syncthreads();  // drains DMA for buf[cb]; buf[cb^1] readers done

    if (t + 1 < NTILES_G) dma(cb ^ 1, t + 1);
    unsigned long long mwnext = 0;
    if (t + 1 < NTILES_G) mwnext = wbp[t + 1];

    // ---- S^T = K Q^T  (A: swizzled Ks rows b128; B: Q regs)
    f32x4 sc[4][2];
#pragma unroll
    for (int nt = 0; nt < 4; ++nt) {
      const _Float16* krow = &smem[g][0][cb][nt * 16 + cl][0];
      const f16x8 a0 = *(const f16x8*)(krow + ((qd ^ sw) << 3));
      const f16x8 a1 = *(const f16x8*)(krow + (((qd + 4) ^ sw) << 3));
#pragma unroll
      for (int mt = 0; mt < 2; ++mt) {
        f32x4 c = zero4;
        c = __builtin_amdgcn_mfma_f32_16x16x32_f16(a0, qf[mt][0], c, 0, 0, 0);
        c = __builtin_amdgcn_mfma_f32_16x16x32_f16(a1, qf[mt][1], c, 0, 0, 0);
        sc[nt][mt] = c;  // q = mt*16+cl, s = ts*64 + nt*16 + qd*4 + r
      }
    }

    // ---- softmax numerator; P stays in registers as PV A-frags
    f16x4 pa[2][4];
    if (mwcur == ~0ull) {  // all-attend fast path
#pragma unroll
      for (int mt = 0; mt < 2; ++mt)
#pragma unroll
        for (int nt = 0; nt < 4; ++nt) {
          f32x4 p;
#pragma unroll
          for (int r = 0; r < 4; ++r)
            p[r] = __builtin_amdgcn_exp2f(sc[nt][mt][r] * SCALE2f);
          rs4[mt] += p;
          H4 u;
          u.h[0] = cvt2(p[0], p[1]);
          u.h[1] = cvt2(p[2], p[3]);
          pa[mt][nt] = u.v;
        }
    } else {
      const unsigned lo = (unsigned)mwcur;
      const unsigned hi = (unsigned)(mwcur >> 32);
#pragma unroll
      for (int mt = 0; mt < 2; ++mt)
#pragma unroll
        for (int nt = 0; nt < 4; ++nt) {
          const unsigned shm = ((nt < 2) ? lo : hi) >> ((nt & 1) * 16 + qd * 4);
          f32x4 p;
#pragma unroll
          for (int r = 0; r < 4; ++r) {
            const float bias = (shm & (1u << r)) ? 0.f : MBIAS2f;
            p[r] = __builtin_amdgcn_exp2f(__builtin_fmaf(sc[nt][mt][r], SCALE2f, bias));
          }
          rs4[mt] += p;
          H4 u;
          u.h[0] = cvt2(p[0], p[1]);
          u.h[1] = cvt2(p[2], p[3]);
          pa[mt][nt] = u.v;
        }
    }

    // ---- O += P V  (A: P regs; B: swizzled Vt rows b64)
#pragma unroll
    for (int nt = 0; nt < 4; ++nt)
#pragma unroll
      for (int et = 0; et < 4; ++et) {
        const _Float16* vrow = &smem[g][1][cb][et * 16 + cl][0];
        const f16x4 bv = *(const f16x4*)(vrow + ((((2 * nt + (qd >> 1)) ^ sw) << 3) + ((qd & 1) << 2)));
        acc[0][et] = __builtin_amdgcn_mfma_f32_16x16x16f16(pa[0][nt], bv, acc[0][et], 0, 0, 0);
        acc[1][et] = __builtin_amdgcn_mfma_f32_16x16x16f16(pa[1][nt], bv, acc[1][et], 0, 0, 0);
      }

    mwcur = mwnext;
  }

  // ---- epilogue: cross-group combine via LDS (no rescale needed: plain sums),
  // group g keeps output cols [g*32, g*32+32) so all 8 waves store.
  __syncthreads();  // all tile reads done; smem reusable
  f32x4* xb = (f32x4*)smem;           // acc exchange: [gd][wq][mt][ei][lane] 32KB
  f32x4* rb = xb + 2 * 4 * 2 * 2 * 64;  // rs exchange: [g][wq][mt][lane] 16KB
  const int gd = 1 - g;
#pragma unroll
  for (int mt = 0; mt < 2; ++mt) {
#pragma unroll
    for (int ei = 0; ei < 2; ++ei)
      xb[((((gd * 4 + wq) * 2 + mt) * 2 + ei) << 6) + lane] = acc[mt][2 * gd + ei];
    rb[(((g * 4 + wq) * 2 + mt) << 6) + lane] = rs4[mt];
  }
  __syncthreads();
#pragma unroll
  for (int mt = 0; mt < 2; ++mt) {
    const f32x4 rsum = rs4[mt] + rb[(((gd * 4 + wq) * 2 + mt) << 6) + lane];
    float v = rsum[0] + rsum[1] + rsum[2] + rsum[3];
    v += __shfl_xor(v, 16, 64);
    v += __shfl_xor(v, 32, 64);  // every lane: full row sum for q = mt*16 + cl
    const f32x4 a0 = acc[mt][2 * g + 0] + xb[((((g * 4 + wq) * 2 + mt) * 2 + 0) << 6) + lane];
    const f32x4 a1 = acc[mt][2 * g + 1] + xb[((((g * 4 + wq) * 2 + mt) * 2 + 1) << 6) + lane];
#pragma unroll
    for (int r = 0; r < 4; ++r) {
      const float invq = 1.0f / __shfl(v, qd * 4 + r, 64);
      const int l = l0 + mt * 16 + qd * 4 + r;
      float* op = Og + ((((size_t)b * H_ + h) * L_ + l) << 6) + cl;
      op[(2 * g + 0) * 16] = a0[r] * invq;
      op[(2 * g + 1) * 16] = a1[r] * invq;
    }
  }
}

extern "C" void kernel_launch(void* const* d_in, const int* in_sizes, int n_in,
                              void* d_out, int out_size, void* d_ws, size_t ws_size,
                              hipStream_t stream) {
  const float* Q = (const float*)d_in[0];
  const float* K = (const float*)d_in[1];
  const float* V = (const float*)d_in[2];
  const float* M = (const float*)d_in[3];
  float* O = (float*)d_out;
  unsigned long long* Wb = (unsigned long long*)d_ws;              // 1 MiB
  _Float16* Khp = (_Float16*)((char*)d_ws + KHOFF);                // 8.39 MB
  _Float16* Vhp = (_Float16*)((char*)d_ws + VHOFF);                // 8.39 MB

  hipLaunchKernelGGL(prep_kernel, dim3(5120), dim3(256), 0, stream, K, V, M, Khp, Vhp, Wb);
  hipLaunchKernelGGL(fattn_kernel, dim3(B_ * H_ * (L_ / MBLK)), dim3(512), 0, stream,
                     Q, Khp, Vhp, Wb, O);
}

// Round 3
// 168.996 us; speedup vs baseline: 1.3876x; 1.3876x over previous
//
#include <hip/hip_runtime.h>

typedef float    f32x4 __attribute__((ext_vector_type(4)));
typedef _Float16 f16x2 __attribute__((ext_vector_type(2)));
typedef _Float16 f16x4 __attribute__((ext_vector_type(4)));
typedef _Float16 f16x8 __attribute__((ext_vector_type(8)));
typedef int      i32x4 __attribute__((ext_vector_type(4)));

namespace {
constexpr int B_ = 2, L_ = 2048, S_ = 2048, H_ = 16, E_ = 64;
constexpr int MBLK = 128;        // q rows per block (4 q-subblocks x 32)
constexpr int NT = 64;           // s-tile width
constexpr int NTILES_G = 16;     // s-tiles per group (32 total / 2 groups)

#define SCALE2f 0.1803368801111204f /* 0.125 * log2(e) */
#define MBIAS2f -1.8033688e8f       /* -1e9 * 0.125 * log2(e): exp2 -> exactly 0 */

// ws layout: [0,1MiB) mask bits | Kh f16 [b,h,s,e] 8.39MB | Vh f16 [b,h,e,s] 8.39MB
constexpr size_t KHOFF = (size_t)1 << 20;
constexpr size_t VHOFF = KHOFF + (size_t)B_ * H_ * S_ * E_ * 2;

__device__ __forceinline__ f16x2 cvt2(float a, float b) {
  return __builtin_bit_cast(f16x2, __builtin_amdgcn_cvt_pkrtz(a, b));
}
__device__ __forceinline__ int pkh(float a, float b) {
  return __builtin_bit_cast(int, __builtin_amdgcn_cvt_pkrtz(a, b));
}
union H8 { f16x8 v; i32x4 i; };
union H4 { f16x4 v; f16x2 h[2]; };

#define GLOAD_LDS16(g, l)                                              \
  __builtin_amdgcn_global_load_lds(                                    \
      (const __attribute__((address_space(1))) void*)(g),              \
      (__attribute__((address_space(3))) void*)(l), 16, 0, 0)
}  // namespace

// ---- fused pre-pass: kcvt [0,2048) | maskpack [2048,4096) | vcvt [4096,5120)
extern "C" __global__ __launch_bounds__(256)
void prep_kernel(const float* __restrict__ Kg, const float* __restrict__ Vg,
                 const float* __restrict__ Mg, _Float16* __restrict__ Kh,
                 _Float16* __restrict__ Vh, unsigned long long* __restrict__ Wb) {
  __shared__ _Float16 T[64][72];
  const int bid = blockIdx.x;
  const int t   = threadIdx.x;

  if (bid < 2048) {
    // K [b,s,h,e] f32 -> Kh [b,h,s,e] f16 (h-gather)
    const int idx = bid * 256 + t;  // 8-e chunk id
    const int j = idx & 7;
    const int h = (idx >> 3) & (H_ - 1);
    const int s = (idx >> 7) & (S_ - 1);
    const int b = idx >> 18;
    const float* src = Kg + ((((size_t)b * S_ + s) * H_ + h) << 6) + j * 8;
    f32x4 x = *(const f32x4*)src, y = *(const f32x4*)(src + 4);
    i32x4 w = {pkh(x[0], x[1]), pkh(x[2], x[3]), pkh(y[0], y[1]), pkh(y[2], y[3])};
    *(i32x4*)(Kh + ((((size_t)b * H_ + h) * S_ + s) << 6) + j * 8) = w;
  } else if (bid < 4096) {
    // mask fp32 -> 1 bit/element; thread: 16 floats (64B coalesced) -> one u16
    const int u = (bid - 2048) * 256 + t;
    const float* src = Mg + (size_t)u * 16;
    unsigned m = 0;
#pragma unroll
    for (int i = 0; i < 4; ++i) {
      f32x4 x = *(const f32x4*)(src + i * 4);
#pragma unroll
      for (int c = 0; c < 4; ++c) m |= (x[c] > 0.5f ? 1u : 0u) << (i * 4 + c);
    }
    ((unsigned short*)Wb)[u] = (unsigned short)m;
  } else {
    // V [b,s,h,e] f32 -> Vh [b,h,e,s] f16 (transpose via LDS)
    const int vb = bid - 4096;  // (b,h,st)
    const int st = vb & 31;
    const int h  = (vb >> 5) & (H_ - 1);
    const int b  = vb >> 9;
    const int sl = t >> 2;
    const int e0 = (t & 3) << 4;
    const float* src = Vg + ((((size_t)b * S_ + st * 64 + sl) * H_ + h) << 6) + e0;
#pragma unroll
    for (int i = 0; i < 4; ++i) {
      f32x4 x = *(const f32x4*)(src + i * 4);
#pragma unroll
      for (int c = 0; c < 4; ++c) T[e0 + i * 4 + c][sl] = (_Float16)x[c];
    }
    __syncthreads();
    const int er = t >> 2;
    const int s0 = (t & 3) << 4;
    _Float16* dst = Vh + (((((size_t)b * H_ + h) << 6) + er) * S_) + st * 64 + s0;
    *(i32x4*)dst       = *(const i32x4*)&T[er][s0];
    *(i32x4*)(dst + 8) = *(const i32x4*)&T[er][s0 + 8];
  }
}

// 8 waves = 2 s-groups x 4 q-subblocks. Each group owns half the s-tiles with
// its own K/V double-buffer -> per-wave LDS reads at the 32-row rate while
// occupancy is 16 waves/CU. NOTE: every register-array subscript below is a
// compile-time constant (runtime-indexed ext_vector arrays demote to scratch
// -- the round-2 regression: 546 MB of scratch writes from acc[..][2*g+ei]).
extern "C" __global__ __launch_bounds__(512, 4)
void fattn_kernel(const float* __restrict__ Qg, const _Float16* __restrict__ Kh,
                  const _Float16* __restrict__ Vh, const unsigned long long* __restrict__ Wb,
                  float* __restrict__ Og) {
  // [group][K=0/V=1][buf][row][64], 64 KB; DMA dest lane-contiguous (no pad),
  // bank safety via XOR-granule swizzle
  __shared__ __align__(16) _Float16 smem[2][2][2][64][64];

  const int tid  = threadIdx.x;
  const int wv   = tid >> 6;   // 0..7
  const int lane = tid & 63;
  const int g    = wv >> 2;    // s-range group: tiles [g*16, g*16+16)
  const int wq   = wv & 3;     // q sub-block (32 rows)
  const int qd   = lane >> 4;
  const int cl   = lane & 15;
  const int sw   = cl & 7;     // reader swizzle key (row & 7)

  // XCD-locality: bid%8 == bh%8 -> all 16 q-blocks of one (b,h) on one XCD
  const int bid = blockIdx.x;
  const int qb  = bid >> 5;
  const int bh  = bid & 31;
  const int h   = bh & (H_ - 1);
  const int b   = bh >> 4;

  const int l0 = qb * MBLK + wq * 32;  // 32 q rows per wave (2 m-tiles)

  // ---- Q fragments (B-operand of S^T = K Q^T), f16, from f32 global
  f16x8 qf[2][2];
#pragma unroll
  for (int mt = 0; mt < 2; ++mt) {
    const float* qp = Qg + ((((size_t)b * L_ + (l0 + mt * 16 + cl)) * H_ + h) << 6);
#pragma unroll
    for (int kb = 0; kb < 2; ++kb) {
      const int e0 = qd * 8 + kb * 32;
      f32x4 x = *(const f32x4*)(qp + e0);
      f32x4 y = *(const f32x4*)(qp + e0 + 4);
      H8 u;
      u.i = (i32x4){pkh(x[0], x[1]), pkh(x[2], x[3]), pkh(y[0], y[1]), pkh(y[2], y[3])};
      qf[mt][kb] = u.v;
    }
  }

  // ---- DMA lane constants: lane = 8*row_local + granule_slot
  const int rl  = lane >> 3;       // row within 8-row slab (0..7)
  const int gsl = lane & 7;        // granule slot in LDS row
  const int gsw = gsl ^ rl;        // swizzled source granule (row&7 == rl)
  const _Float16* khb = Kh + ((((size_t)b * H_ + h) * S_) << 6);          // [s][e]
  const _Float16* vhb = Vh + ((((size_t)b * H_ + h) << 6) * (size_t)S_);  // [e][s]

  const unsigned long long* wbp = Wb + (((size_t)b * L_ + (l0 + cl)) << 5) + g * NTILES_G;

  // stage one tile of this group's K+V via global_load_lds (16 B/lane)
  auto dma = [&](int buf, int t) {
    const int ts = g * NTILES_G + t;
#pragma unroll
    for (int p = 0; p < 2; ++p) {
      const int r0 = p * 32 + wq * 8;
      const _Float16* ksrc = khb + (((size_t)(ts * 64 + r0 + rl)) << 6) + gsw * 8;
      GLOAD_LDS16(ksrc, &smem[g][0][buf][r0][0]);
      const _Float16* vsrc = vhb + (size_t)(r0 + rl) * S_ + ts * 64 + gsw * 8;
      GLOAD_LDS16(vsrc, &smem[g][1][buf][r0][0]);
    }
  };

  const f32x4 zero4 = {0.f, 0.f, 0.f, 0.f};
  f32x4 acc[2][4];
#pragma unroll
  for (int mt = 0; mt < 2; ++mt)
#pragma unroll
    for (int et = 0; et < 4; ++et) acc[mt][et] = zero4;
  f32x4 rs4[2] = {zero4, zero4};

  dma(0, 0);
  unsigned long long mwcur = wbp[0];

  for (int t = 0; t < NTILES_G; ++t) {
    const int cb = t & 1;
    __syncthreads();  // drains DMA for buf[cb]; buf[cb^1] readers done

    if (t + 1 < NTILES_G) dma(cb ^ 1, t + 1);
    unsigned long long mwnext = 0;
    if (t + 1 < NTILES_G) mwnext = wbp[t + 1];

    // ---- S^T = K Q^T  (A: swizzled Ks rows b128; B: Q regs)
    f32x4 sc[4][2];
#pragma unroll
    for (int nt = 0; nt < 4; ++nt) {
      const _Float16* krow = &smem[g][0][cb][nt * 16 + cl][0];
      const f16x8 a0 = *(const f16x8*)(krow + ((qd ^ sw) << 3));
      const f16x8 a1 = *(const f16x8*)(krow + (((qd + 4) ^ sw) << 3));
#pragma unroll
      for (int mt = 0; mt < 2; ++mt) {
        f32x4 c = zero4;
        c = __builtin_amdgcn_mfma_f32_16x16x32_f16(a0, qf[mt][0], c, 0, 0, 0);
        c = __builtin_amdgcn_mfma_f32_16x16x32_f16(a1, qf[mt][1], c, 0, 0, 0);
        sc[nt][mt] = c;  // q = mt*16+cl, s = ts*64 + nt*16 + qd*4 + r
      }
    }

    // ---- softmax numerator; P stays in registers as PV A-frags
    f16x4 pa[2][4];
    if (mwcur == ~0ull) {  // all-attend fast path
#pragma unroll
      for (int mt = 0; mt < 2; ++mt)
#pragma unroll
        for (int nt = 0; nt < 4; ++nt) {
          f32x4 p;
#pragma unroll
          for (int r = 0; r < 4; ++r)
            p[r] = __builtin_amdgcn_exp2f(sc[nt][mt][r] * SCALE2f);
          rs4[mt] += p;
          H4 u;
          u.h[0] = cvt2(p[0], p[1]);
          u.h[1] = cvt2(p[2], p[3]);
          pa[mt][nt] = u.v;
        }
    } else {
      const unsigned lo = (unsigned)mwcur;
      const unsigned hi = (unsigned)(mwcur >> 32);
#pragma unroll
      for (int mt = 0; mt < 2; ++mt)
#pragma unroll
        for (int nt = 0; nt < 4; ++nt) {
          const unsigned shm = ((nt < 2) ? lo : hi) >> ((nt & 1) * 16 + qd * 4);
          f32x4 p;
#pragma unroll
          for (int r = 0; r < 4; ++r) {
            const float bias = (shm & (1u << r)) ? 0.f : MBIAS2f;
            p[r] = __builtin_amdgcn_exp2f(__builtin_fmaf(sc[nt][mt][r], SCALE2f, bias));
          }
          rs4[mt] += p;
          H4 u;
          u.h[0] = cvt2(p[0], p[1]);
          u.h[1] = cvt2(p[2], p[3]);
          pa[mt][nt] = u.v;
        }
    }

    // ---- O += P V  (A: P regs; B: swizzled Vt rows b64)
#pragma unroll
    for (int nt = 0; nt < 4; ++nt)
#pragma unroll
      for (int et = 0; et < 4; ++et) {
        const _Float16* vrow = &smem[g][1][cb][et * 16 + cl][0];
        const f16x4 bv = *(const f16x4*)(vrow + ((((2 * nt + (qd >> 1)) ^ sw) << 3) + ((qd & 1) << 2)));
        acc[0][et] = __builtin_amdgcn_mfma_f32_16x16x16f16(pa[0][nt], bv, acc[0][et], 0, 0, 0);
        acc[1][et] = __builtin_amdgcn_mfma_f32_16x16x16f16(pa[1][nt], bv, acc[1][et], 0, 0, 0);
      }

    mwcur = mwnext;
  }

  // ---- epilogue: cross-group combine via LDS (plain sums, no rescale).
  // group g keeps output cols [g*32, g*32+32). All acc subscripts are
  // compile-time; g-dependence goes through wave-uniform selects.
  __syncthreads();  // all tile reads done; smem reusable
  f32x4* xb = (f32x4*)smem;             // acc exchange: [gdst][wq][mt][ei][lane] 32KB
  f32x4* rb = xb + 2 * 4 * 2 * 2 * 64;  // rs exchange: [g][wq][mt][lane] 16KB
  const int gd = 1 - g;
#pragma unroll
  for (int mt = 0; mt < 2; ++mt) {
    const f32x4 ho0 = g ? acc[mt][0] : acc[mt][2];  // chunks for partner's cols
    const f32x4 ho1 = g ? acc[mt][1] : acc[mt][3];
    xb[((((gd * 4 + wq) * 2 + mt) * 2 + 0) << 6) + lane] = ho0;
    xb[((((gd * 4 + wq) * 2 + mt) * 2 + 1) << 6) + lane] = ho1;
    rb[(((g * 4 + wq) * 2 + mt) << 6) + lane] = rs4[mt];
  }
  __syncthreads();
#pragma unroll
  for (int mt = 0; mt < 2; ++mt) {
    const f32x4 rsum = rs4[mt] + rb[(((gd * 4 + wq) * 2 + mt) << 6) + lane];
    float v = rsum[0] + rsum[1] + rsum[2] + rsum[3];
    v += __shfl_xor(v, 16, 64);
    v += __shfl_xor(v, 32, 64);  // every lane: full row sum for q = mt*16 + cl
    const f32x4 m0 = g ? acc[mt][2] : acc[mt][0];   // own-column chunks
    const f32x4 m1 = g ? acc[mt][3] : acc[mt][1];
    const f32x4 a0 = m0 + xb[((((g * 4 + wq) * 2 + mt) * 2 + 0) << 6) + lane];
    const f32x4 a1 = m1 + xb[((((g * 4 + wq) * 2 + mt) * 2 + 1) << 6) + lane];
#pragma unroll
    for (int r = 0; r < 4; ++r) {
      const float invq = 1.0f / __shfl(v, qd * 4 + r, 64);
      const int l = l0 + mt * 16 + qd * 4 + r;
      float* op = Og + ((((size_t)b * H_ + h) * L_ + l) << 6) + cl;
      op[(2 * g + 0) * 16] = a0[r] * invq;
      op[(2 * g + 1) * 16] = a1[r] * invq;
    }
  }
}

extern "C" void kernel_launch(void* const* d_in, const int* in_sizes, int n_in,
                              void* d_out, int out_size, void* d_ws, size_t ws_size,
                              hipStream_t stream) {
  const float* Q = (const float*)d_in[0];
  const float* K = (const float*)d_in[1];
  const float* V = (const float*)d_in[2];
  const float* M = (const float*)d_in[3];
  float* O = (float*)d_out;
  unsigned long long* Wb = (unsigned long long*)d_ws;              // 1 MiB
  _Float16* Khp = (_Float16*)((char*)d_ws + KHOFF);                // 8.39 MB
  _Float16* Vhp = (_Float16*)((char*)d_ws + VHOFF);                // 8.39 MB

  hipLaunchKernelGGL(prep_kernel, dim3(5120), dim3(256), 0, stream, K, V, M, Khp, Vhp, Wb);
  hipLaunchKernelGGL(fattn_kernel, dim3(B_ * H_ * (L_ / MBLK)), dim3(512), 0, stream,
                     Q, Khp, Vhp, Wb, O);
}

// Round 4
// 168.331 us; speedup vs baseline: 1.3931x; 1.0040x over previous
//
#include <hip/hip_runtime.h>

typedef float    f32x4 __attribute__((ext_vector_type(4)));
typedef _Float16 f16x2 __attribute__((ext_vector_type(2)));
typedef _Float16 f16x4 __attribute__((ext_vector_type(4)));
typedef _Float16 f16x8 __attribute__((ext_vector_type(8)));
typedef int      i32x4 __attribute__((ext_vector_type(4)));

namespace {
constexpr int B_ = 2, L_ = 2048, S_ = 2048, H_ = 16, E_ = 64;
constexpr int MBLK = 128;        // q rows per block (8 waves x 16)
constexpr int NT = 64;           // s-tile width
constexpr int NTILES = S_ / NT;  // 32

#define SCALE2f 0.1803368801111204f /* 0.125 * log2(e) */
#define MBIAS2f -1.8033688e8f       /* -1e9 * 0.125 * log2(e): exp2 -> exactly 0 */

// ws layout: [0,1MiB) mask bits | Kh f16 [b,h,s,e] 8.39MB | Vh f16 [b,h,e,s] 8.39MB
constexpr size_t KHOFF = (size_t)1 << 20;
constexpr size_t VHOFF = KHOFF + (size_t)B_ * H_ * S_ * E_ * 2;

__device__ __forceinline__ f16x2 cvt2(float a, float b) {
  return __builtin_bit_cast(f16x2, __builtin_amdgcn_cvt_pkrtz(a, b));
}
__device__ __forceinline__ int pkh(float a, float b) {
  return __builtin_bit_cast(int, __builtin_amdgcn_cvt_pkrtz(a, b));
}
union H8 { f16x8 v; i32x4 i; };
union H4 { f16x4 v; f16x2 h[2]; };

#define GLOAD_LDS16(g, l)                                              \
  __builtin_amdgcn_global_load_lds(                                    \
      (const __attribute__((address_space(1))) void*)(g),              \
      (__attribute__((address_space(3))) void*)(l), 16, 0, 0)
}  // namespace

// ---- fused pre-pass: kcvt [0,2048) | maskpack [2048,4096) | vcvt [4096,5120)
extern "C" __global__ __launch_bounds__(256)
void prep_kernel(const float* __restrict__ Kg, const float* __restrict__ Vg,
                 const float* __restrict__ Mg, _Float16* __restrict__ Kh,
                 _Float16* __restrict__ Vh, unsigned long long* __restrict__ Wb) {
  __shared__ _Float16 T[64][72];
  const int bid = blockIdx.x;
  const int t   = threadIdx.x;

  if (bid < 2048) {
    // K [b,s,h,e] f32 -> Kh [b,h,s,e] f16 (h-gather)
    const int idx = bid * 256 + t;  // 8-e chunk id
    const int j = idx & 7;
    const int h = (idx >> 3) & (H_ - 1);
    const int s = (idx >> 7) & (S_ - 1);
    const int b = idx >> 18;
    const float* src = Kg + ((((size_t)b * S_ + s) * H_ + h) << 6) + j * 8;
    f32x4 x = *(const f32x4*)src, y = *(const f32x4*)(src + 4);
    i32x4 w = {pkh(x[0], x[1]), pkh(x[2], x[3]), pkh(y[0], y[1]), pkh(y[2], y[3])};
    *(i32x4*)(Kh + ((((size_t)b * H_ + h) * S_ + s) << 6) + j * 8) = w;
  } else if (bid < 4096) {
    // mask fp32 -> 1 bit/element; thread: 16 floats (64B coalesced) -> one u16
    const int u = (bid - 2048) * 256 + t;
    const float* src = Mg + (size_t)u * 16;
    unsigned m = 0;
#pragma unroll
    for (int i = 0; i < 4; ++i) {
      f32x4 x = *(const f32x4*)(src + i * 4);
#pragma unroll
      for (int c = 0; c < 4; ++c) m |= (x[c] > 0.5f ? 1u : 0u) << (i * 4 + c);
    }
    ((unsigned short*)Wb)[u] = (unsigned short)m;
  } else {
    // V [b,s,h,e] f32 -> Vh [b,h,e,s] f16 (transpose via LDS)
    const int vb = bid - 4096;  // (b,h,st)
    const int st = vb & 31;
    const int h  = (vb >> 5) & (H_ - 1);
    const int b  = vb >> 9;
    const int sl = t >> 2;
    const int e0 = (t & 3) << 4;
    const float* src = Vg + ((((size_t)b * S_ + st * 64 + sl) * H_ + h) << 6) + e0;
#pragma unroll
    for (int i = 0; i < 4; ++i) {
      f32x4 x = *(const f32x4*)(src + i * 4);
#pragma unroll
      for (int c = 0; c < 4; ++c) T[e0 + i * 4 + c][sl] = (_Float16)x[c];
    }
    __syncthreads();
    const int er = t >> 2;
    const int s0 = (t & 3) << 4;
    _Float16* dst = Vh + (((((size_t)b * H_ + h) << 6) + er) * S_) + st * 64 + s0;
    *(i32x4*)dst       = *(const i32x4*)&T[er][s0];
    *(i32x4*)(dst + 8) = *(const i32x4*)&T[er][s0 + 8];
  }
}

// Round-1 wave layout (8 waves x 16 q-rows) + tri-buffered K/V staging +
// counted-vmcnt raw barriers (T3/T4): tile t+2's DMA rides through the
// barrier (never vmcnt(0) in the main loop); each iteration issues exactly
// 3 VMEM ops (mask u64 + K gload_lds + V gload_lds), regions pinned by
// memory-clobber asm, so vmcnt(3) at iter t == "region t-2 fully landed".
extern "C" __global__ __launch_bounds__(512, 4)
void fattn_kernel(const float* __restrict__ Qg, const _Float16* __restrict__ Kh,
                  const _Float16* __restrict__ Vh, const unsigned long long* __restrict__ Wb,
                  float* __restrict__ Og) {
  // tri-buffer: [buf][row][64], 24 KB each; DMA dest lane-contiguous (no pad),
  // bank safety via XOR-granule swizzle
  __shared__ __align__(16) _Float16 Ks[3][NT][64];
  __shared__ __align__(16) _Float16 Vt[3][E_][64];

  const int tid  = threadIdx.x;
  const int wv   = tid >> 6;   // 0..7
  const int lane = tid & 63;
  const int qd   = lane >> 4;
  const int cl   = lane & 15;
  const int sw   = cl & 7;     // reader swizzle key (row & 7)

  // XCD-locality: bid%8 == bh%8 -> all 16 q-blocks of one (b,h) on one XCD
  const int bid = blockIdx.x;
  const int qb  = bid >> 5;
  const int bh  = bid & 31;
  const int h   = bh & (H_ - 1);
  const int b   = bh >> 4;

  const int l0 = qb * MBLK + wv * 16;  // 16 q rows per wave

  // ---- Q fragments (B-operand of S^T = K Q^T), f16, from f32 global
  f16x8 qf[2];
  {
    const float* qp = Qg + ((((size_t)b * L_ + (l0 + cl)) * H_ + h) << 6);
#pragma unroll
    for (int kb = 0; kb < 2; ++kb) {
      const int e0 = qd * 8 + kb * 32;
      f32x4 x = *(const f32x4*)(qp + e0);
      f32x4 y = *(const f32x4*)(qp + e0 + 4);
      H8 u;
      u.i = (i32x4){pkh(x[0], x[1]), pkh(x[2], x[3]), pkh(y[0], y[1]), pkh(y[2], y[3])};
      qf[kb] = u.v;
    }
  }

  // ---- DMA lane constants: lane = 8*row_local + granule_slot
  const int rl  = lane >> 3;       // row within wave's 8-row slab (0..7)
  const int gsl = lane & 7;        // granule slot in LDS row
  const int gsw = gsl ^ rl;        // swizzled source granule (row&7 == rl)
  const _Float16* khb = Kh + ((((size_t)b * H_ + h) * S_) << 6);          // [s][e]
  const _Float16* vhb = Vh + ((((size_t)b * H_ + h) << 6) * (size_t)S_);  // [e][s]

  const unsigned long long* wbp = Wb + (((size_t)b * L_ + (l0 + cl)) << 5);

  // stage one tile's K+V (16 B/lane, 8 rows/wave each): exactly 2 VMEM ops
  auto dma = [&](int buf, int t) {
    const int r0 = wv * 8;
    const _Float16* ksrc = khb + (((size_t)(t * 64 + r0 + rl)) << 6) + gsw * 8;
    GLOAD_LDS16(ksrc, &Ks[buf][r0][0]);
    const _Float16* vsrc = vhb + (size_t)(r0 + rl) * S_ + t * 64 + gsw * 8;
    GLOAD_LDS16(vsrc, &Vt[buf][r0][0]);
  };

  const f32x4 zero4 = {0.f, 0.f, 0.f, 0.f};
  f32x4 acc[4];
#pragma unroll
  for (int et = 0; et < 4; ++et) acc[et] = zero4;
  f32x4 rs4 = zero4;

  // ---- prologue: two regions, fenced so vmcnt counting stays exact
  unsigned long long mwcur = wbp[0];   // region -2: mask0 + dma(0) = 3 VMEM
  dma(0, 0);
  asm volatile("" ::: "memory");
  __builtin_amdgcn_sched_barrier(0);
  unsigned long long mwnext = wbp[1];  // region -1: mask1 + dma(1) = 3 VMEM
  dma(1, 1);

  int bc = 0;  // t % 3
  for (int t = 0; t < NTILES; ++t) {
    __builtin_amdgcn_sched_barrier(0);
    // wait: region t-2 (tile t's K,V,mask) landed; region t-1 (3 ops) in flight
    if (t < NTILES - 1)
      asm volatile("s_waitcnt vmcnt(3) lgkmcnt(0)" ::: "memory");
    else
      asm volatile("s_waitcnt vmcnt(0) lgkmcnt(0)" ::: "memory");
    __builtin_amdgcn_s_barrier();
    __builtin_amdgcn_sched_barrier(0);

    // region t: issue tile t+2 (3 VMEM ops, order within region irrelevant)
    unsigned long long mwnext2 = 0;
    if (t + 2 < NTILES) {
      int b2 = bc + 2; if (b2 >= 3) b2 -= 3;
      mwnext2 = wbp[t + 2];
      dma(b2, t + 2);
    }

    // ---- S^T = K Q^T  (A: swizzled Ks rows b128; B: Q regs)
    f32x4 sc[4];
    __builtin_amdgcn_s_setprio(1);
#pragma unroll
    for (int nt = 0; nt < 4; ++nt) {
      const _Float16* krow = &Ks[bc][nt * 16 + cl][0];
      const f16x8 a0 = *(const f16x8*)(krow + ((qd ^ sw) << 3));
      const f16x8 a1 = *(const f16x8*)(krow + (((qd + 4) ^ sw) << 3));
      f32x4 c = zero4;
      c = __builtin_amdgcn_mfma_f32_16x16x32_f16(a0, qf[0], c, 0, 0, 0);
      c = __builtin_amdgcn_mfma_f32_16x16x32_f16(a1, qf[1], c, 0, 0, 0);
      sc[nt] = c;  // q = cl, s = nt*16 + qd*4 + r
    }
    __builtin_amdgcn_s_setprio(0);

    // ---- softmax numerator; P stays in registers as PV A-frags
    f16x4 pa[4];
    if (mwcur == ~0ull) {  // all-attend fast path
#pragma unroll
      for (int nt = 0; nt < 4; ++nt) {
        f32x4 p;
#pragma unroll
        for (int r = 0; r < 4; ++r)
          p[r] = __builtin_amdgcn_exp2f(sc[nt][r] * SCALE2f);
        rs4 += p;
        H4 u;
        u.h[0] = cvt2(p[0], p[1]);
        u.h[1] = cvt2(p[2], p[3]);
        pa[nt] = u.v;
      }
    } else {
      const unsigned lo = (unsigned)mwcur;
      const unsigned hi = (unsigned)(mwcur >> 32);
#pragma unroll
      for (int nt = 0; nt < 4; ++nt) {
        const unsigned shm = ((nt < 2) ? lo : hi) >> ((nt & 1) * 16 + qd * 4);
        f32x4 p;
#pragma unroll
        for (int r = 0; r < 4; ++r) {
          const float bias = (shm & (1u << r)) ? 0.f : MBIAS2f;
          p[r] = __builtin_amdgcn_exp2f(__builtin_fmaf(sc[nt][r], SCALE2f, bias));
        }
        rs4 += p;
        H4 u;
        u.h[0] = cvt2(p[0], p[1]);
        u.h[1] = cvt2(p[2], p[3]);
        pa[nt] = u.v;
      }
    }

    // ---- O += P V  (A: P regs; B: swizzled Vt rows b64)
    __builtin_amdgcn_s_setprio(1);
#pragma unroll
    for (int nt = 0; nt < 4; ++nt)
#pragma unroll
      for (int et = 0; et < 4; ++et) {
        const _Float16* vrow = &Vt[bc][et * 16 + cl][0];
        const f16x4 bv = *(const f16x4*)(vrow + ((((2 * nt + (qd >> 1)) ^ sw) << 3) + ((qd & 1) << 2)));
        acc[et] = __builtin_amdgcn_mfma_f32_16x16x16f16(pa[nt], bv, acc[et], 0, 0, 0);
      }
    __builtin_amdgcn_s_setprio(0);

    mwcur = mwnext;
    mwnext = mwnext2;
    bc = (bc + 1 == 3) ? 0 : bc + 1;
  }

  // ---- epilogue: row-sum reduce, broadcast inv per q-row, store
  {
    float v = rs4[0] + rs4[1] + rs4[2] + rs4[3];
    v += __shfl_xor(v, 16, 64);
    v += __shfl_xor(v, 32, 64);  // every lane: sum for q = cl
#pragma unroll
    for (int r = 0; r < 4; ++r) {
      const float invq = 1.0f / __shfl(v, qd * 4 + r, 64);
      const int l = l0 + qd * 4 + r;
      float* op = Og + ((((size_t)b * H_ + h) * L_ + l) << 6) + cl;
#pragma unroll
      for (int et = 0; et < 4; ++et) op[et * 16] = acc[et][r] * invq;
    }
  }
}

extern "C" void kernel_launch(void* const* d_in, const int* in_sizes, int n_in,
                              void* d_out, int out_size, void* d_ws, size_t ws_size,
                              hipStream_t stream) {
  const float* Q = (const float*)d_in[0];
  const float* K = (const float*)d_in[1];
  const float* V = (const float*)d_in[2];
  const float* M = (const float*)d_in[3];
  float* O = (float*)d_out;
  unsigned long long* Wb = (unsigned long long*)d_ws;              // 1 MiB
  _Float16* Khp = (_Float16*)((char*)d_ws + KHOFF);                // 8.39 MB
  _Float16* Vhp = (_Float16*)((char*)d_ws + VHOFF);                // 8.39 MB

  hipLaunchKernelGGL(prep_kernel, dim3(5120), dim3(256), 0, stream, K, V, M, Khp, Vhp, Wb);
  hipLaunchKernelGGL(fattn_kernel, dim3(B_ * H_ * (L_ / MBLK)), dim3(512), 0, stream,
                     Q, Khp, Vhp, Wb, O);
}